// Round 1
// baseline (604.202 us; speedup 1.0000x reference)
//
#include <hip/hip_runtime.h>
#include <cstdint>
#include <cmath>

#define B_ 2
#define N_ 4096
#define D_ 128
#define H_ 16
#define DQK_ 64
#define DV_ 256

typedef float    f4_t __attribute__((ext_vector_type(4)));
typedef _Float16 h4_t __attribute__((ext_vector_type(4)));
typedef _Float16 h8_t __attribute__((ext_vector_type(8)));

__device__ __forceinline__ float sigmoidf_(float z) { return 1.f/(1.f + expf(-z)); }
__device__ __forceinline__ float siluf_(float z)    { return z/(1.f + expf(-z)); }

// ---------------- EMA: s[t] = q*s[t-1] + a*exp[h,d]*x[t], chunked scan ----------------
// grid 1024 = 2(b) * 64(chunk) * 8(dgroup); block 256 = 16h x 16d
__global__ void ema_phase1(const float* __restrict__ x, const float* __restrict__ expansion,
                           const float* __restrict__ alphas, const float* __restrict__ dampen,
                           float* __restrict__ F) {
  int bid = blockIdx.x;
  int dg = bid & 7, c = (bid >> 3) & 63, b = bid >> 9;
  int h = threadIdx.x & 15, dl = threadIdx.x >> 4;
  int d = dg*16 + dl;
  float a  = sigmoidf_(alphas[h]);
  float dm = sigmoidf_(dampen[h]);
  float q  = (1.f - a)*dm;
  float coef = a * expansion[h*D_ + d];
  __shared__ float xs[64][16];
  {
    int e = threadIdx.x;                 // 1024 floats / 256 thr = 1 float4 each
    int t = e >> 2, seg = e & 3;
    const float* xp = x + ((size_t)b*N_ + c*64 + t)*D_ + dg*16 + seg*4;
    *(f4_t*)&xs[t][seg*4] = *(const f4_t*)xp;
  }
  __syncthreads();
  float s = 0.f;
#pragma unroll
  for (int t = 0; t < 64; ++t) s = fmaf(q, s, coef*xs[t][dl]);
  F[(((size_t)b*H_ + h)*D_ + d)*64 + c] = s;
}

// grid 16 x 256 = 4096 threads = one per (b,h,d)
__global__ void ema_carry(const float* __restrict__ F, const float* __restrict__ alphas,
                          const float* __restrict__ dampen, float* __restrict__ carry) {
  int idx = blockIdx.x*256 + threadIdx.x;     // (b*16+h)*128 + d
  int h = (idx >> 7) & 15;
  float a  = sigmoidf_(alphas[h]);
  float dm = sigmoidf_(dampen[h]);
  float q  = (1.f - a)*dm;
  float qL = q;
#pragma unroll
  for (int i = 0; i < 6; ++i) qL *= qL;       // q^64
  const float* Fp = F + (size_t)idx*64;
  float* cp = carry + (size_t)idx*64;
  float s = 0.f;
  for (int cc = 0; cc < 64; ++cc) { cp[cc] = s; s = fmaf(qL, s, Fp[cc]); }
}

// same grid as phase1; fuses reduction over h into ema[b,t,d]
__global__ void ema_phase2(const float* __restrict__ x, const float* __restrict__ expansion,
                           const float* __restrict__ reduction,
                           const float* __restrict__ alphas, const float* __restrict__ dampen,
                           const float* __restrict__ carry, float* __restrict__ ema) {
  int bid = blockIdx.x;
  int dg = bid & 7, c = (bid >> 3) & 63, b = bid >> 9;
  int h = threadIdx.x & 15, dl = threadIdx.x >> 4;
  int d = dg*16 + dl;
  float a  = sigmoidf_(alphas[h]);
  float dm = sigmoidf_(dampen[h]);
  float q  = (1.f - a)*dm;
  float coef = a * expansion[h*D_ + d];
  float red  = reduction[h*D_ + d];
  __shared__ float xs[64][16];
  {
    int e = threadIdx.x;
    int t = e >> 2, seg = e & 3;
    const float* xp = x + ((size_t)b*N_ + c*64 + t)*D_ + dg*16 + seg*4;
    *(f4_t*)&xs[t][seg*4] = *(const f4_t*)xp;
  }
  __syncthreads();
  float s = carry[(((size_t)b*H_ + h)*D_ + d)*64 + c];
  for (int t = 0; t < 64; ++t) {
    s = fmaf(q, s, coef*xs[t][dl]);
    float v = red * s;
    v += __shfl_xor(v, 1); v += __shfl_xor(v, 2);
    v += __shfl_xor(v, 4); v += __shfl_xor(v, 8);
    if (h == 0) ema[((size_t)b*N_ + c*64 + t)*D_ + d] = v;
  }
}

// ---------------- rel-pos bias lookup table: bias[delta] ----------------
__global__ void bias_table(const float* __restrict__ rel_table, float* __restrict__ biasT) {
  int r = blockIdx.x*256 + threadIdx.x;       // 0..4095
  int bucket;
  if (r < 16) bucket = r;
  else {
    double v = log((double)r / 16.0) / log(8.0) * 16.0;
    bucket = 16 + (int)v;
    if (bucket > 31) bucket = 31;
  }
  biasT[r] = rel_table[bucket] * 8.0f;        // * sqrt(DQK)
}

// ---------------- fused linears: qk/q/k, v, reset, update, hema ----------------
// grid = 128 rowtiles * 13 slabs, block = 64 (one wave). Lane = output column.
// W column cached in VGPRs; source rows read as wave-uniform scalar loads.
__global__ __launch_bounds__(64) void linear_all(
    const float* __restrict__ ema, const float* __restrict__ x,
    const float* __restrict__ Wqk, const float* __restrict__ bqk,
    const float* __restrict__ gamma, const float* __restrict__ beta,
    const float* __restrict__ Wv, const float* __restrict__ bv,
    const float* __restrict__ Wr, const float* __restrict__ br,
    const float* __restrict__ Wu, const float* __restrict__ bu,
    const float* __restrict__ Wh, const float* __restrict__ bh,
    _Float16* __restrict__ qh, _Float16* __restrict__ kh, _Float16* __restrict__ vh,
    float* __restrict__ resetb, float* __restrict__ updateb, float* __restrict__ hemab) {
  int rt = blockIdx.x / 13, slab = blockIdx.x % 13;
  int lane = threadIdx.x;
  int row0 = rt*64;
  const float* W; const float* bias; const float* src; int ncol, c0, mode;
  if (slab == 0)      { W=Wqk; bias=bqk; src=ema; ncol=64;  c0=0;            mode=0; }
  else if (slab < 5)  { W=Wv;  bias=bv;  src=x;   ncol=256; c0=(slab-1)*64;  mode=1; }
  else if (slab < 9)  { W=Wr;  bias=br;  src=ema; ncol=256; c0=(slab-5)*64;  mode=2; }
  else if (slab < 11) { W=Wu;  bias=bu;  src=ema; ncol=128; c0=(slab-9)*64;  mode=3; }
  else                { W=Wh;  bias=bh;  src=ema; ncol=128; c0=(slab-11)*64; mode=4; }
  int c = c0 + lane;
  float wreg[128];
#pragma unroll
  for (int d0 = 0; d0 < 128; ++d0) wreg[d0] = W[d0*ncol + c];
  float bv_ = bias[c];
  float g0 = 0.f, g1 = 0.f, be0 = 0.f, be1 = 0.f;
  if (mode == 0) { g0 = gamma[lane]; g1 = gamma[64+lane]; be0 = beta[lane]; be1 = beta[64+lane]; }
  for (int r = 0; r < 64; ++r) {
    const float* srow = src + (size_t)(row0 + r)*D_;
    float a0 = bv_, a1 = 0.f, a2 = 0.f, a3 = 0.f;
#pragma unroll
    for (int d = 0; d < 128; d += 4) {
      a0 = fmaf(srow[d+0], wreg[d+0], a0);
      a1 = fmaf(srow[d+1], wreg[d+1], a1);
      a2 = fmaf(srow[d+2], wreg[d+2], a2);
      a3 = fmaf(srow[d+3], wreg[d+3], a3);
    }
    float acc = (a0+a1)+(a2+a3);
    size_t row = row0 + r;
    if (mode == 0) {
      float qk = siluf_(acc);
      qh[row*DQK_ + c] = (_Float16)(qk*g0 + be0);
      kh[row*DQK_ + c] = (_Float16)(qk*g1 + be1);
    } else if (mode == 1) {
      vh[row*DV_ + c] = (_Float16)siluf_(acc);
    } else if (mode == 2) {
      resetb[row*DV_ + c] = siluf_(acc);
    } else if (mode == 3) {
      updateb[row*D_ + c] = sigmoidf_(acc);
    } else {
      hemab[row*D_ + c] = acc;                 // includes bh; silu applied in final
    }
  }
}

// ---------------- attention: laplacian(QK^T/n + bias[i-j]) @ V, causal ----------------
// grid 256 = 2(b) * 64(i-tile of 64 rows) * 2(j-half, split-K). block 256 = 4 waves x 16 rows.
__global__ __launch_bounds__(256) void attn_kernel(
    const _Float16* __restrict__ qh, const _Float16* __restrict__ kh,
    const _Float16* __restrict__ vh, const float* __restrict__ biasT,
    float* __restrict__ attnp) {
  int bid = blockIdx.x;
  int half = bid & 1;
  int it = (bid >> 1) & 63;
  int b = bid >> 7;
  int i0 = it * 64;
  int lane = threadIdx.x & 63, wave = threadIdx.x >> 6;
  int lr = lane & 15, lg = lane >> 4;

  __shared__ _Float16 Klds[64][72];
  __shared__ __align__(16) _Float16 Vlds[64*264];
  __shared__ _Float16 Plds[4][16][68];

  h4_t qf[4];
  {
    const _Float16* qp = qh + ((size_t)b*N_ + i0 + wave*16 + lr)*DQK_;
#pragma unroll
    for (int ks = 0; ks < 4; ++ks) qf[ks] = *(const h4_t*)(qp + ks*16 + lg*4);
  }
  f4_t accO[16];
#pragma unroll
  for (int i = 0; i < 16; ++i) accO[i] = (f4_t){0.f,0.f,0.f,0.f};

  int njt = it + 1;
  int jlo = half ? (njt >> 1) : 0;
  int jhi = half ? njt : (njt >> 1);
  const int vswz = lg << 4;   // = ((vrow>>2)&3)<<4 for this lane's V-frag rows

  for (int jt = jlo; jt < jhi; ++jt) {
    int j0 = jt * 64;
    __syncthreads();
    {
      const h8_t* ks8 = (const h8_t*)(kh + ((size_t)b*N_ + j0)*DQK_);
#pragma unroll
      for (int i = 0; i < 2; ++i) {
        int idx = threadIdx.x + i*256;
        int row = idx >> 3, seg = idx & 7;
        *(h8_t*)&Klds[row][seg*8] = ks8[idx];
      }
      const h8_t* vs8 = (const h8_t*)(vh + ((size_t)b*N_ + j0)*DV_);
#pragma unroll
      for (int i = 0; i < 8; ++i) {
        int idx = threadIdx.x + i*256;
        int row = idx >> 5, seg = idx & 31;
        int boff = (row*528 + seg*16) ^ (((row >> 2) & 3) << 4);  // bank swizzle
        *(h8_t*)((char*)Vlds + boff) = vs8[idx];
      }
    }
    __syncthreads();

    // S = Q K^T (16 rows per wave), epilogue -> P (f16) in per-wave LDS
#pragma unroll
    for (int ns = 0; ns < 4; ++ns) {
      f4_t accS = (f4_t){0.f,0.f,0.f,0.f};
#pragma unroll
      for (int ks = 0; ks < 4; ++ks) {
        h4_t bf = *(const h4_t*)&Klds[ns*16 + lr][ks*16 + lg*4];
        accS = __builtin_amdgcn_mfma_f32_16x16x16f16(qf[ks], bf, accS, 0, 0, 0);
      }
      int jcol = j0 + ns*16 + lr;
#pragma unroll
      for (int r = 0; r < 4; ++r) {
        int irow = i0 + wave*16 + lg*4 + r;
        float pv = 0.f;
        if (jcol <= irow) {
          float z = accS[r]*(1.f/4096.f) + biasT[irow - jcol];
          pv = 0.5f*(1.f + erff((z - 0.70710678f)*0.79788456f));
        }
        Plds[wave][lg*4 + r][ns*16 + lr] = (_Float16)pv;
      }
    }

    // O += P @ V
#pragma unroll
    for (int ks = 0; ks < 4; ++ks) {
      h4_t pa = *(const h4_t*)&Plds[wave][lr][ks*16 + lg*4];
#pragma unroll
      for (int ns2 = 0; ns2 < 16; ++ns2) {
        h4_t vf;
#pragma unroll
        for (int e = 0; e < 4; ++e) {
          int vrow = ks*16 + lg*4 + e;
          int boff = (vrow*528 + (ns2*16 + lr)*2) ^ vswz;
          vf[e] = *(const _Float16*)((const char*)Vlds + boff);
        }
        accO[ns2] = __builtin_amdgcn_mfma_f32_16x16x16f16(pa, vf, accO[ns2], 0, 0, 0);
      }
    }
  }

  float* op = attnp + (((size_t)half*B_ + b)*N_)*DV_;
#pragma unroll
  for (int ns2 = 0; ns2 < 16; ++ns2) {
#pragma unroll
    for (int r = 0; r < 4; ++r) {
      int irow = i0 + wave*16 + lg*4 + r;
      op[(size_t)irow*DV_ + ns2*16 + lr] = accO[ns2][r];
    }
  }
}

// gated = (attn_half0 + attn_half1) * reset
__global__ void combine_gated(const float* __restrict__ a0, const float* __restrict__ a1,
                              const float* __restrict__ resetb, float* __restrict__ gated) {
  size_t i = (size_t)blockIdx.x*256 + threadIdx.x;
  f4_t v0 = ((const f4_t*)a0)[i];
  f4_t v1 = ((const f4_t*)a1)[i];
  f4_t r  = ((const f4_t*)resetb)[i];
  ((f4_t*)gated)[i] = (v0 + v1) * r;
}

// ---------------- final: H = silu(hema + gated@Uh (+bh already in hema)); out = u*H+(1-u)*x
// grid 1024 = 512 rowtiles(16 rows) * 2 colslabs(64). block = 1 wave; lane = out column.
__global__ __launch_bounds__(64) void final_kernel(
    const float* __restrict__ gated, const float* __restrict__ Uh,
    const float* __restrict__ hemab, const float* __restrict__ updateb,
    const float* __restrict__ x, float* __restrict__ out) {
  int rt = blockIdx.x >> 1, cs = blockIdx.x & 1;
  int r0 = rt * 16;
  int c = cs*64 + threadIdx.x;
  float acc[16];
#pragma unroll
  for (int r = 0; r < 16; ++r) acc[r] = 0.f;
#pragma unroll 1
  for (int kc = 0; kc < 4; ++kc) {
    float wreg[64];
#pragma unroll
    for (int kk = 0; kk < 64; ++kk) wreg[kk] = Uh[(kc*64 + kk)*D_ + c];
#pragma unroll
    for (int r = 0; r < 16; ++r) {
      const float* g = gated + (size_t)(r0 + r)*DV_ + kc*64;
#pragma unroll
      for (int kk = 0; kk < 64; ++kk) acc[r] = fmaf(g[kk], wreg[kk], acc[r]);
    }
  }
#pragma unroll
  for (int r = 0; r < 16; ++r) {
    size_t row = r0 + r;
    float z = acc[r] + hemab[row*D_ + c];
    float Hv = siluf_(z);
    float u  = updateb[row*D_ + c];
    float xv = x[row*D_ + c];
    out[row*D_ + c] = u*Hv + (1.f - u)*xv;
  }
}

extern "C" void kernel_launch(void* const* d_in, const int* in_sizes, int n_in,
                              void* d_out, int out_size, void* d_ws, size_t ws_size,
                              hipStream_t stream) {
  (void)in_sizes; (void)n_in; (void)out_size; (void)ws_size;
  const float* x         = (const float*)d_in[0];
  const float* expansion = (const float*)d_in[1];
  const float* reduction = (const float*)d_in[2];
  const float* alphas    = (const float*)d_in[3];
  const float* dampen    = (const float*)d_in[4];
  const float* Wqk       = (const float*)d_in[5];
  const float* bqk       = (const float*)d_in[6];
  const float* gamma     = (const float*)d_in[7];
  const float* beta      = (const float*)d_in[8];
  const float* Wv        = (const float*)d_in[9];
  const float* bv        = (const float*)d_in[10];
  const float* rel_table = (const float*)d_in[11];
  const float* Wr        = (const float*)d_in[12];
  const float* br        = (const float*)d_in[13];
  const float* Wu        = (const float*)d_in[14];
  const float* bu        = (const float*)d_in[15];
  const float* Wh        = (const float*)d_in[16];
  const float* Uh        = (const float*)d_in[17];
  const float* bh        = (const float*)d_in[18];
  float* out = (float*)d_out;

  char* p = (char*)d_ws;
  size_t off = 0;
  auto alloc = [&](size_t bytes) -> char* {
    char* r = p + off;
    off += (bytes + 255) & ~(size_t)255;
    return r;
  };
  float*    F      = (float*)alloc((size_t)B_*H_*D_*64*4);
  float*    carry  = (float*)alloc((size_t)B_*H_*D_*64*4);
  float*    ema    = (float*)alloc((size_t)B_*N_*D_*4);
  float*    biasT  = (float*)alloc((size_t)N_*4);
  _Float16* qh     = (_Float16*)alloc((size_t)B_*N_*DQK_*2);
  _Float16* kh     = (_Float16*)alloc((size_t)B_*N_*DQK_*2);
  _Float16* vh     = (_Float16*)alloc((size_t)B_*N_*DV_*2);
  float*    resetb = (float*)alloc((size_t)B_*N_*DV_*4);
  float*    updateb= (float*)alloc((size_t)B_*N_*D_*4);
  float*    hemab  = (float*)alloc((size_t)B_*N_*D_*4);
  float*    gated  = (float*)alloc((size_t)B_*N_*DV_*4);
  float*    attnp  = (float*)alloc((size_t)2*B_*N_*DV_*4);

  ema_phase1<<<1024, 256, 0, stream>>>(x, expansion, alphas, dampen, F);
  ema_carry<<<16, 256, 0, stream>>>(F, alphas, dampen, carry);
  ema_phase2<<<1024, 256, 0, stream>>>(x, expansion, reduction, alphas, dampen, carry, ema);
  bias_table<<<16, 256, 0, stream>>>(rel_table, biasT);
  linear_all<<<128*13, 64, 0, stream>>>(ema, x, Wqk, bqk, gamma, beta, Wv, bv, Wr, br,
                                        Wu, bu, Wh, bh, qh, kh, vh, resetb, updateb, hemab);
  attn_kernel<<<256, 256, 0, stream>>>(qh, kh, vh, biasT, attnp);
  combine_gated<<<2048, 256, 0, stream>>>(attnp, attnp + (size_t)B_*N_*DV_, resetb, gated);
  final_kernel<<<1024, 64, 0, stream>>>(gated, Uh, hemab, updateb, x, out);
}

// Round 2
// 208.685 us; speedup vs baseline: 2.8953x; 2.8953x over previous
//
#include <hip/hip_runtime.h>
#include <cstdint>
#include <cmath>

#define B_ 2
#define N_ 4096
#define D_ 128
#define H_ 16
#define DQK_ 64
#define DV_ 256

typedef float    f4_t __attribute__((ext_vector_type(4)));
typedef _Float16 h4_t __attribute__((ext_vector_type(4)));
typedef _Float16 h8_t __attribute__((ext_vector_type(8)));

__device__ __forceinline__ float sigmoidf_(float z) { return 1.f/(1.f + expf(-z)); }
__device__ __forceinline__ float siluf_(float z)    { return z/(1.f + expf(-z)); }

// ---------------- EMA: s[t] = q*s[t-1] + a*exp[h,d]*x[t], chunked scan ----------------
// grid 1024 = 2(b) * 64(chunk) * 8(dgroup); block 256 = 16h x 16d. Also emits xh (f16 x).
__global__ void ema_phase1(const float* __restrict__ x, const float* __restrict__ expansion,
                           const float* __restrict__ alphas, const float* __restrict__ dampen,
                           float* __restrict__ F, _Float16* __restrict__ xh) {
  int bid = blockIdx.x;
  int dg = bid & 7, c = (bid >> 3) & 63, b = bid >> 9;
  int h = threadIdx.x & 15, dl = threadIdx.x >> 4;
  int d = dg*16 + dl;
  float a  = sigmoidf_(alphas[h]);
  float dm = sigmoidf_(dampen[h]);
  float q  = (1.f - a)*dm;
  float coef = a * expansion[h*D_ + d];
  __shared__ float xs[64][16];
  {
    int e = threadIdx.x;                 // 1024 floats / 256 thr = 1 float4 each
    int t = e >> 2, seg = e & 3;
    const float* xp = x + ((size_t)b*N_ + c*64 + t)*D_ + dg*16 + seg*4;
    f4_t v = *(const f4_t*)xp;
    *(f4_t*)&xs[t][seg*4] = v;
    h4_t hv;
#pragma unroll
    for (int j = 0; j < 4; ++j) hv[j] = (_Float16)v[j];
    *(h4_t*)(xh + ((size_t)b*N_ + c*64 + t)*D_ + dg*16 + seg*4) = hv;
  }
  __syncthreads();
  float s = 0.f;
#pragma unroll
  for (int t = 0; t < 64; ++t) s = fmaf(q, s, coef*xs[t][dl]);
  F[(((size_t)b*H_ + h)*D_ + d)*64 + c] = s;
}

// grid 16 x 256 = 4096 threads = one per (b,h,d)
__global__ void ema_carry(const float* __restrict__ F, const float* __restrict__ alphas,
                          const float* __restrict__ dampen, float* __restrict__ carry) {
  int idx = blockIdx.x*256 + threadIdx.x;     // (b*16+h)*128 + d
  int h = (idx >> 7) & 15;
  float a  = sigmoidf_(alphas[h]);
  float dm = sigmoidf_(dampen[h]);
  float q  = (1.f - a)*dm;
  float qL = q;
#pragma unroll
  for (int i = 0; i < 6; ++i) qL *= qL;       // q^64
  const float* Fp = F + (size_t)idx*64;
  float* cp = carry + (size_t)idx*64;
  float s = 0.f;
  for (int cc = 0; cc < 64; ++cc) { cp[cc] = s; s = fmaf(qL, s, Fp[cc]); }
}

// same grid as phase1; fuses reduction over h into ema[b,t,d] (f32 + f16 copies)
__global__ void ema_phase2(const float* __restrict__ x, const float* __restrict__ expansion,
                           const float* __restrict__ reduction,
                           const float* __restrict__ alphas, const float* __restrict__ dampen,
                           const float* __restrict__ carry, float* __restrict__ ema,
                           _Float16* __restrict__ emah) {
  int bid = blockIdx.x;
  int dg = bid & 7, c = (bid >> 3) & 63, b = bid >> 9;
  int h = threadIdx.x & 15, dl = threadIdx.x >> 4;
  int d = dg*16 + dl;
  float a  = sigmoidf_(alphas[h]);
  float dm = sigmoidf_(dampen[h]);
  float q  = (1.f - a)*dm;
  float coef = a * expansion[h*D_ + d];
  float red  = reduction[h*D_ + d];
  __shared__ float xs[64][16];
  {
    int e = threadIdx.x;
    int t = e >> 2, seg = e & 3;
    const float* xp = x + ((size_t)b*N_ + c*64 + t)*D_ + dg*16 + seg*4;
    *(f4_t*)&xs[t][seg*4] = *(const f4_t*)xp;
  }
  __syncthreads();
  float s = carry[(((size_t)b*H_ + h)*D_ + d)*64 + c];
  for (int t = 0; t < 64; ++t) {
    s = fmaf(q, s, coef*xs[t][dl]);
    float v = red * s;
    v += __shfl_xor(v, 1); v += __shfl_xor(v, 2);
    v += __shfl_xor(v, 4); v += __shfl_xor(v, 8);
    if (h == 0) {
      size_t o = ((size_t)b*N_ + c*64 + t)*D_ + d;
      ema[o] = v;
      emah[o] = (_Float16)v;
    }
  }
}

// ---------------- rel-pos bias lookup table: bias[delta] ----------------
__global__ void bias_table(const float* __restrict__ rel_table, float* __restrict__ biasT) {
  int r = blockIdx.x*256 + threadIdx.x;       // 0..4095
  int bucket;
  if (r < 16) bucket = r;
  else {
    double v = log((double)r / 16.0) / log(8.0) * 16.0;
    bucket = 16 + (int)v;
    if (bucket > 31) bucket = 31;
  }
  biasT[r] = rel_table[bucket] * 8.0f;        // * sqrt(DQK)
}

// ---------------- weight prep: Wt[832][128] f16 (transposed concat), bcat[832] ----------------
__global__ void prep_weights(const float* __restrict__ Wqk, const float* __restrict__ Wv,
                             const float* __restrict__ Wr, const float* __restrict__ Wu,
                             const float* __restrict__ Wh,
                             const float* __restrict__ bqk, const float* __restrict__ bv,
                             const float* __restrict__ br, const float* __restrict__ bu,
                             const float* __restrict__ bh,
                             _Float16* __restrict__ Wt, float* __restrict__ bcat) {
  int idx = blockIdx.x*256 + threadIdx.x;     // 832*128
  if (idx >= 832*128) return;
  int c = idx >> 7, d = idx & 127;
  const float* W; const float* bias; int ncol, cl;
  if (c < 64)       { W=Wqk; bias=bqk; ncol=64;  cl=c; }
  else if (c < 320) { W=Wv;  bias=bv;  ncol=256; cl=c-64; }
  else if (c < 576) { W=Wr;  bias=br;  ncol=256; cl=c-320; }
  else if (c < 704) { W=Wu;  bias=bu;  ncol=128; cl=c-576; }
  else              { W=Wh;  bias=bh;  ncol=128; cl=c-704; }
  Wt[idx] = (_Float16)W[d*ncol + cl];
  if (d == 0) bcat[c] = bias[cl];
}

// ---------------- fused linears as MFMA GEMM: [8192 x 128] @ [128 x 832] ----------------
// grid = 128 rowtiles * 13 slabs, block 256 = 4 waves; wave w -> rows w*16.
__global__ __launch_bounds__(256) void linear_mfma(
    const _Float16* __restrict__ emah, const _Float16* __restrict__ xh,
    const _Float16* __restrict__ Wt, const float* __restrict__ bcat,
    const float* __restrict__ gamma, const float* __restrict__ beta,
    _Float16* __restrict__ qh, _Float16* __restrict__ kh, _Float16* __restrict__ vT,
    float* __restrict__ resetb, float* __restrict__ updateb, float* __restrict__ hemab) {
  int slab = blockIdx.x % 13, rt = blockIdx.x / 13;
  int tid = threadIdx.x;
  int lane = tid & 63, w = tid >> 6;
  int lr = lane & 15, lg = lane >> 4;
  int mode = (slab==0)?0:(slab<5)?1:(slab<9)?2:(slab<11)?3:4;
  const _Float16* src = (mode==1) ? xh : emah;
  __shared__ _Float16 As[64][136];
  __shared__ _Float16 Ws[64][136];
  {
    const h8_t* s8 = (const h8_t*)(src + (size_t)rt*64*D_);
#pragma unroll
    for (int i = 0; i < 4; ++i) {
      int idx = tid + i*256;
      int row = idx >> 4, seg = idx & 15;
      *(h8_t*)&As[row][seg*8] = s8[idx];
    }
    const h8_t* w8 = (const h8_t*)(Wt + (size_t)slab*64*D_);
#pragma unroll
    for (int i = 0; i < 4; ++i) {
      int idx = tid + i*256;
      int row = idx >> 4, seg = idx & 15;
      *(h8_t*)&Ws[row][seg*8] = w8[idx];
    }
  }
  __syncthreads();
  h4_t af[8];
#pragma unroll
  for (int ks = 0; ks < 8; ++ks) af[ks] = *(const h4_t*)&As[w*16 + lr][ks*16 + lg*4];
  int row0 = rt*64 + w*16 + lg*4;              // + r
#pragma unroll
  for (int ns = 0; ns < 4; ++ns) {
    f4_t acc = (f4_t){0.f,0.f,0.f,0.f};
#pragma unroll
    for (int ks = 0; ks < 8; ++ks) {
      h4_t bf = *(const h4_t*)&Ws[ns*16 + lr][ks*16 + lg*4];
      acc = __builtin_amdgcn_mfma_f32_16x16x16f16(af[ks], bf, acc, 0, 0, 0);
    }
    int c = slab*64 + ns*16 + lr;
    float bias = bcat[c];
    if (mode == 0) {
      float g0 = gamma[c], g1 = gamma[64+c], be0 = beta[c], be1 = beta[64+c];
#pragma unroll
      for (int r = 0; r < 4; ++r) {
        float qk = siluf_(acc[r] + bias);
        size_t row = row0 + r;
        qh[row*DQK_ + c] = (_Float16)(qk*g0 + be0);
        kh[row*DQK_ + c] = (_Float16)(qk*g1 + be1);
      }
    } else if (mode == 1) {
      int cl = c - 64;
      int bb = row0 >> 12, rl = row0 & 4095;
      h4_t vv;
#pragma unroll
      for (int r = 0; r < 4; ++r) vv[r] = (_Float16)siluf_(acc[r] + bias);
      *(h4_t*)&vT[((size_t)bb*DV_ + cl)*N_ + rl] = vv;
    } else if (mode == 2) {
      int cl = c - 320;
#pragma unroll
      for (int r = 0; r < 4; ++r) resetb[(size_t)(row0 + r)*DV_ + cl] = siluf_(acc[r] + bias);
    } else if (mode == 3) {
      int cl = c - 576;
#pragma unroll
      for (int r = 0; r < 4; ++r) updateb[(size_t)(row0 + r)*D_ + cl] = sigmoidf_(acc[r] + bias);
    } else {
      int cl = c - 704;
#pragma unroll
      for (int r = 0; r < 4; ++r) hemab[(size_t)(row0 + r)*D_ + cl] = acc[r] + bias;
    }
  }
}

// ---------------- attention: laplacian(QK^T/n + bias[i-j]) @ V, causal ----------------
// grid 1024 = 64(it, largest-first) x 8(split) x 2(b). block 256 = 4 waves x 16 rows.
// Swapped MFMA: S^T = mfma(K, Q) puts P directly in the PV A-fragment layout.
__global__ __launch_bounds__(256) void attn_kernel(
    const _Float16* __restrict__ qh, const _Float16* __restrict__ kh,
    const _Float16* __restrict__ vT, const float* __restrict__ biasT,
    float* __restrict__ attnp) {
  int bid = blockIdx.x;
  int b = bid & 1;
  int s = (bid >> 1) & 7;
  int it = 63 - (bid >> 4);
  int njt = it + 1;
  int nblk = (njt + 7) >> 3;
  if (s >= nblk) return;
  int jlo = s*8, jhi = min(jlo + 8, njt);
  int q_ = it >> 3, r_ = it & 7;
  int slot = 4*q_*(q_+1) + r_*(q_+1) + s;       // compact partial index
  int i0 = it * 64;
  int lane = threadIdx.x & 63, w = threadIdx.x >> 6;
  int lr = lane & 15, lg = lane >> 4;

  __shared__ _Float16 Klds[64][72];
  __shared__ _Float16 VTs[256][72];

  h4_t qf[4];
  const _Float16* qp = qh + ((size_t)b*N_ + i0 + w*16 + lr)*DQK_;
#pragma unroll
  for (int ks = 0; ks < 4; ++ks) qf[ks] = *(const h4_t*)(qp + ks*16 + lg*4);

  f4_t accO[16];
#pragma unroll
  for (int i = 0; i < 16; ++i) accO[i] = (f4_t){0.f,0.f,0.f,0.f};

  for (int jt = jlo; jt < jhi; ++jt) {
    int j0 = jt * 64;
    __syncthreads();
    {
      const h8_t* k8 = (const h8_t*)(kh + ((size_t)b*N_ + j0)*DQK_);
#pragma unroll
      for (int i = 0; i < 2; ++i) {
        int idx = threadIdx.x + i*256;
        int row = idx >> 3, seg = idx & 7;
        *(h8_t*)&Klds[row][seg*8] = k8[idx];
      }
      const _Float16* vtb = vT + (size_t)b*DV_*N_ + j0;
#pragma unroll
      for (int i = 0; i < 8; ++i) {
        int idx = threadIdx.x + i*256;
        int row = idx >> 3, seg = idx & 7;
        *(h8_t*)&VTs[row][seg*8] = *(const h8_t*)(vtb + (size_t)row*N_ + seg*8);
      }
    }
    __syncthreads();

#pragma unroll
    for (int ns = 0; ns < 4; ++ns) {
      // S^T block: rows j, cols i  (A = K rows, B = Q^T)
      f4_t accS = (f4_t){0.f,0.f,0.f,0.f};
#pragma unroll
      for (int ks = 0; ks < 4; ++ks) {
        h4_t kf = *(const h4_t*)&Klds[ns*16 + lr][ks*16 + lg*4];
        accS = __builtin_amdgcn_mfma_f32_16x16x16f16(kf, qf[ks], accS, 0, 0, 0);
      }
      int jbase = j0 + ns*16 + lg*4;            // + r
      int irow  = i0 + w*16 + lr;
      h4_t pa;
#pragma unroll
      for (int r = 0; r < 4; ++r) {
        int delta = irow - (jbase + r);
        int dd = delta < 0 ? 0 : delta;
        float z = accS[r]*(1.f/4096.f) + biasT[dd];
        float pv = 0.5f*(1.f + erff((z - 0.70710678f)*0.79788456f));
        pa[r] = (_Float16)(delta < 0 ? 0.f : pv);
      }
      // O += P(:, this 16-j-slice) @ V(this 16-j-slice, :)
#pragma unroll
      for (int ns2 = 0; ns2 < 16; ++ns2) {
        h4_t vf = *(const h4_t*)&VTs[ns2*16 + lr][ns*16 + lg*4];
        accO[ns2] = __builtin_amdgcn_mfma_f32_16x16x16f16(pa, vf, accO[ns2], 0, 0, 0);
      }
    }
  }

  float* op = attnp + ((size_t)b*288 + slot)*64*DV_;
#pragma unroll
  for (int ns2 = 0; ns2 < 16; ++ns2) {
#pragma unroll
    for (int r = 0; r < 4; ++r) {
      op[(size_t)(w*16 + lg*4 + r)*DV_ + ns2*16 + lr] = accO[ns2][r];
    }
  }
}

// gated = (sum of valid attn partials) * reset
__global__ void combine_gated(const float* __restrict__ attnp, const float* __restrict__ resetb,
                              float* __restrict__ gated) {
  size_t fi = (size_t)blockIdx.x*256 + threadIdx.x;   // f4 index over 8192*256
  int rr = (int)(fi >> 6);
  int c4 = (int)(fi & 63);
  int b = rr >> 12, rowInB = rr & 4095;
  int it = rowInB >> 6, rowLocal = rowInB & 63;
  int nblk = (it + 8) >> 3;
  int q_ = it >> 3, r_ = it & 7;
  int base = 4*q_*(q_+1) + r_*(q_+1);
  const f4_t* ap = (const f4_t*)attnp;
  size_t rowOff = ((size_t)b*288 + base)*64 + rowLocal;
  f4_t acc = (f4_t){0.f,0.f,0.f,0.f};
  for (int s = 0; s < nblk; ++s)
    acc += ap[(rowOff + (size_t)s*64)*64 + c4];
  f4_t rg = ((const f4_t*)resetb)[fi];
  ((f4_t*)gated)[fi] = acc * rg;
}

// ---------------- final: H = silu(hemab + gated@Uh); out = u*H + (1-u)*x ----------------
// grid 1024 = 512 rowtiles(16 rows) * 2 colslabs(64). block = 1 wave; lane = out column.
__global__ __launch_bounds__(64) void final_kernel(
    const float* __restrict__ gated, const float* __restrict__ Uh,
    const float* __restrict__ hemab, const float* __restrict__ updateb,
    const float* __restrict__ x, float* __restrict__ out) {
  int rt = blockIdx.x >> 1, cs = blockIdx.x & 1;
  int r0 = rt * 16;
  int c = cs*64 + threadIdx.x;
  float acc[16];
#pragma unroll
  for (int r = 0; r < 16; ++r) acc[r] = 0.f;
#pragma unroll 1
  for (int kc = 0; kc < 4; ++kc) {
    float wreg[64];
#pragma unroll
    for (int kk = 0; kk < 64; ++kk) wreg[kk] = Uh[(kc*64 + kk)*D_ + c];
#pragma unroll
    for (int r = 0; r < 16; ++r) {
      const float* g = gated + (size_t)(r0 + r)*DV_ + kc*64;
#pragma unroll
      for (int kk = 0; kk < 64; ++kk) acc[r] = fmaf(g[kk], wreg[kk], acc[r]);
    }
  }
#pragma unroll
  for (int r = 0; r < 16; ++r) {
    size_t row = r0 + r;
    float z = acc[r] + hemab[row*D_ + c];
    float Hv = siluf_(z);
    float u  = updateb[row*D_ + c];
    float xv = x[row*D_ + c];
    out[row*D_ + c] = u*Hv + (1.f - u)*xv;
  }
}

extern "C" void kernel_launch(void* const* d_in, const int* in_sizes, int n_in,
                              void* d_out, int out_size, void* d_ws, size_t ws_size,
                              hipStream_t stream) {
  (void)in_sizes; (void)n_in; (void)out_size; (void)ws_size;
  const float* x         = (const float*)d_in[0];
  const float* expansion = (const float*)d_in[1];
  const float* reduction = (const float*)d_in[2];
  const float* alphas    = (const float*)d_in[3];
  const float* dampen    = (const float*)d_in[4];
  const float* Wqk       = (const float*)d_in[5];
  const float* bqk       = (const float*)d_in[6];
  const float* gamma     = (const float*)d_in[7];
  const float* beta      = (const float*)d_in[8];
  const float* Wv        = (const float*)d_in[9];
  const float* bv        = (const float*)d_in[10];
  const float* rel_table = (const float*)d_in[11];
  const float* Wr        = (const float*)d_in[12];
  const float* br        = (const float*)d_in[13];
  const float* Wu        = (const float*)d_in[14];
  const float* bu        = (const float*)d_in[15];
  const float* Wh        = (const float*)d_in[16];
  const float* Uh        = (const float*)d_in[17];
  const float* bh        = (const float*)d_in[18];
  float* out = (float*)d_out;

  char* p = (char*)d_ws;
  size_t off = 0;
  auto alloc = [&](size_t bytes) -> char* {
    char* r = p + off;
    off += (bytes + 255) & ~(size_t)255;
    return r;
  };
  float*    F      = (float*)alloc((size_t)B_*H_*D_*64*4);
  float*    carry  = (float*)alloc((size_t)B_*H_*D_*64*4);
  float*    ema    = (float*)alloc((size_t)B_*N_*D_*4);
  _Float16* emah   = (_Float16*)alloc((size_t)B_*N_*D_*2);
  _Float16* xh     = (_Float16*)alloc((size_t)B_*N_*D_*2);
  float*    biasT  = (float*)alloc((size_t)N_*4);
  _Float16* Wt     = (_Float16*)alloc((size_t)832*128*2);
  float*    bcat   = (float*)alloc((size_t)832*4);
  _Float16* qh     = (_Float16*)alloc((size_t)B_*N_*DQK_*2);
  _Float16* kh     = (_Float16*)alloc((size_t)B_*N_*DQK_*2);
  _Float16* vT     = (_Float16*)alloc((size_t)B_*DV_*N_*2);
  float*    resetb = (float*)alloc((size_t)B_*N_*DV_*4);
  float*    updateb= (float*)alloc((size_t)B_*N_*D_*4);
  float*    hemab  = (float*)alloc((size_t)B_*N_*D_*4);
  float*    gated  = (float*)alloc((size_t)B_*N_*DV_*4);
  float*    attnp  = (float*)alloc((size_t)B_*288*64*DV_*4);

  prep_weights<<<416, 256, 0, stream>>>(Wqk, Wv, Wr, Wu, Wh, bqk, bv, br, bu, bh, Wt, bcat);
  bias_table<<<16, 256, 0, stream>>>(rel_table, biasT);
  ema_phase1<<<1024, 256, 0, stream>>>(x, expansion, alphas, dampen, F, xh);
  ema_carry<<<16, 256, 0, stream>>>(F, alphas, dampen, carry);
  ema_phase2<<<1024, 256, 0, stream>>>(x, expansion, reduction, alphas, dampen, carry, ema, emah);
  linear_mfma<<<128*13, 256, 0, stream>>>(emah, xh, Wt, bcat, gamma, beta,
                                          qh, kh, vT, resetb, updateb, hemab);
  attn_kernel<<<1024, 256, 0, stream>>>(qh, kh, vT, biasT, attnp);
  combine_gated<<<2048, 256, 0, stream>>>(attnp, resetb, gated);
  final_kernel<<<1024, 64, 0, stream>>>(gated, Uh, hemab, updateb, x, out);
}

// Round 3
// 138.969 us; speedup vs baseline: 4.3477x; 1.5017x over previous
//
#include <hip/hip_runtime.h>
#include <cstdint>
#include <cmath>

#define B_ 2
#define N_ 4096
#define D_ 128
#define H_ 16
#define DQK_ 64
#define DV_ 256

typedef float    f4_t __attribute__((ext_vector_type(4)));
typedef _Float16 h4_t __attribute__((ext_vector_type(4)));
typedef _Float16 h8_t __attribute__((ext_vector_type(8)));

__device__ __forceinline__ float sigmoidf_(float z) { return 1.f/(1.f + expf(-z)); }
__device__ __forceinline__ float siluf_(float z)    { return z/(1.f + expf(-z)); }

// ---------------- EMA: s[t] = q*s[t-1] + a*exp[h,d]*x[t], chunked scan ----------------
// grid 1024 = 2(b) * 64(chunk) * 8(dgroup); block 256 = 16h x 16d. Also emits xh (f16 x).
__global__ void ema_phase1(const float* __restrict__ x, const float* __restrict__ expansion,
                           const float* __restrict__ alphas, const float* __restrict__ dampen,
                           float* __restrict__ F, _Float16* __restrict__ xh) {
  int bid = blockIdx.x;
  int dg = bid & 7, c = (bid >> 3) & 63, b = bid >> 9;
  int h = threadIdx.x & 15, dl = threadIdx.x >> 4;
  int d = dg*16 + dl;
  float a  = sigmoidf_(alphas[h]);
  float dm = sigmoidf_(dampen[h]);
  float q  = (1.f - a)*dm;
  float coef = a * expansion[h*D_ + d];
  __shared__ float xs[64][16];
  {
    int e = threadIdx.x;                 // 1024 floats / 256 thr = 1 float4 each
    int t = e >> 2, seg = e & 3;
    const float* xp = x + ((size_t)b*N_ + c*64 + t)*D_ + dg*16 + seg*4;
    f4_t v = *(const f4_t*)xp;
    *(f4_t*)&xs[t][seg*4] = v;
    h4_t hv;
#pragma unroll
    for (int j = 0; j < 4; ++j) hv[j] = (_Float16)v[j];
    *(h4_t*)(xh + ((size_t)b*N_ + c*64 + t)*D_ + dg*16 + seg*4) = hv;
  }
  __syncthreads();
  float s = 0.f;
#pragma unroll
  for (int t = 0; t < 64; ++t) s = fmaf(q, s, coef*xs[t][dl]);
  F[(((size_t)b*H_ + h)*D_ + d)*64 + c] = s;
}

// grid 16 x 256 = 4096 threads = one per (b,h,d)
__global__ void ema_carry(const float* __restrict__ F, const float* __restrict__ alphas,
                          const float* __restrict__ dampen, float* __restrict__ carry) {
  int idx = blockIdx.x*256 + threadIdx.x;     // (b*16+h)*128 + d
  int h = (idx >> 7) & 15;
  float a  = sigmoidf_(alphas[h]);
  float dm = sigmoidf_(dampen[h]);
  float q  = (1.f - a)*dm;
  float qL = q;
#pragma unroll
  for (int i = 0; i < 6; ++i) qL *= qL;       // q^64
  const float* Fp = F + (size_t)idx*64;
  float* cp = carry + (size_t)idx*64;
  float s = 0.f;
  for (int cc = 0; cc < 64; ++cc) { cp[cc] = s; s = fmaf(qL, s, Fp[cc]); }
}

// same grid as phase1; fuses reduction over h into ema[b,t,d] (f32 + f16 copies)
__global__ void ema_phase2(const float* __restrict__ x, const float* __restrict__ expansion,
                           const float* __restrict__ reduction,
                           const float* __restrict__ alphas, const float* __restrict__ dampen,
                           const float* __restrict__ carry, float* __restrict__ ema,
                           _Float16* __restrict__ emah) {
  int bid = blockIdx.x;
  int dg = bid & 7, c = (bid >> 3) & 63, b = bid >> 9;
  int h = threadIdx.x & 15, dl = threadIdx.x >> 4;
  int d = dg*16 + dl;
  float a  = sigmoidf_(alphas[h]);
  float dm = sigmoidf_(dampen[h]);
  float q  = (1.f - a)*dm;
  float coef = a * expansion[h*D_ + d];
  float red  = reduction[h*D_ + d];
  __shared__ float xs[64][16];
  {
    int e = threadIdx.x;
    int t = e >> 2, seg = e & 3;
    const float* xp = x + ((size_t)b*N_ + c*64 + t)*D_ + dg*16 + seg*4;
    *(f4_t*)&xs[t][seg*4] = *(const f4_t*)xp;
  }
  __syncthreads();
  float s = carry[(((size_t)b*H_ + h)*D_ + d)*64 + c];
  for (int t = 0; t < 64; ++t) {
    s = fmaf(q, s, coef*xs[t][dl]);
    float v = red * s;
    v += __shfl_xor(v, 1); v += __shfl_xor(v, 2);
    v += __shfl_xor(v, 4); v += __shfl_xor(v, 8);
    if (h == 0) {
      size_t o = ((size_t)b*N_ + c*64 + t)*D_ + d;
      ema[o] = v;
      emah[o] = (_Float16)v;
    }
  }
}

// ---------------- rel-pos bias lookup table: bias[delta] ----------------
__global__ void bias_table(const float* __restrict__ rel_table, float* __restrict__ biasT) {
  int r = blockIdx.x*256 + threadIdx.x;       // 0..4095
  int bucket;
  if (r < 16) bucket = r;
  else {
    double v = log((double)r / 16.0) / log(8.0) * 16.0;
    bucket = 16 + (int)v;
    if (bucket > 31) bucket = 31;
  }
  biasT[r] = rel_table[bucket] * 8.0f;        // * sqrt(DQK)
}

// ---------------- weight prep: Wt[832][128] f16 (transposed concat), bcat[832] ----------------
__global__ void prep_weights(const float* __restrict__ Wqk, const float* __restrict__ Wv,
                             const float* __restrict__ Wr, const float* __restrict__ Wu,
                             const float* __restrict__ Wh,
                             const float* __restrict__ bqk, const float* __restrict__ bv,
                             const float* __restrict__ br, const float* __restrict__ bu,
                             const float* __restrict__ bh,
                             _Float16* __restrict__ Wt, float* __restrict__ bcat) {
  int idx = blockIdx.x*256 + threadIdx.x;     // 832*128
  if (idx >= 832*128) return;
  int c = idx >> 7, d = idx & 127;
  const float* W; const float* bias; int ncol, cl;
  if (c < 64)       { W=Wqk; bias=bqk; ncol=64;  cl=c; }
  else if (c < 320) { W=Wv;  bias=bv;  ncol=256; cl=c-64; }
  else if (c < 576) { W=Wr;  bias=br;  ncol=256; cl=c-320; }
  else if (c < 704) { W=Wu;  bias=bu;  ncol=128; cl=c-576; }
  else              { W=Wh;  bias=bh;  ncol=128; cl=c-704; }
  Wt[idx] = (_Float16)W[d*ncol + cl];
  if (d == 0) bcat[c] = bias[cl];
}

// Uht[c][k] = Uh[k][c] as f16.  grid 128 x 256
__global__ void prep_uh(const float* __restrict__ Uh, _Float16* __restrict__ Uht) {
  int idx = blockIdx.x*256 + threadIdx.x;     // 32768 = 256k x 128c
  int k = idx >> 7, c = idx & 127;
  Uht[(size_t)c*256 + k] = (_Float16)Uh[idx];
}

// ---------------- fused linears as MFMA GEMM: [8192 x 128] @ [128 x 832] ----------------
// grid = 128 rowtiles * 13 slabs, block 256 = 4 waves; wave w -> rows w*16.
__global__ __launch_bounds__(256) void linear_mfma(
    const _Float16* __restrict__ emah, const _Float16* __restrict__ xh,
    const _Float16* __restrict__ Wt, const float* __restrict__ bcat,
    const float* __restrict__ gamma, const float* __restrict__ beta,
    _Float16* __restrict__ qh, _Float16* __restrict__ kh, _Float16* __restrict__ vT,
    float* __restrict__ resetb, float* __restrict__ updateb, float* __restrict__ hemab) {
  int slab = blockIdx.x % 13, rt = blockIdx.x / 13;
  int tid = threadIdx.x;
  int lane = tid & 63, w = tid >> 6;
  int lr = lane & 15, lg = lane >> 4;
  int mode = (slab==0)?0:(slab<5)?1:(slab<9)?2:(slab<11)?3:4;
  const _Float16* src = (mode==1) ? xh : emah;
  __shared__ _Float16 As[64][136];
  __shared__ _Float16 Ws[64][136];
  {
    const h8_t* s8 = (const h8_t*)(src + (size_t)rt*64*D_);
#pragma unroll
    for (int i = 0; i < 4; ++i) {
      int idx = tid + i*256;
      int row = idx >> 4, seg = idx & 15;
      *(h8_t*)&As[row][seg*8] = s8[idx];
    }
    const h8_t* w8 = (const h8_t*)(Wt + (size_t)slab*64*D_);
#pragma unroll
    for (int i = 0; i < 4; ++i) {
      int idx = tid + i*256;
      int row = idx >> 4, seg = idx & 15;
      *(h8_t*)&Ws[row][seg*8] = w8[idx];
    }
  }
  __syncthreads();
  h4_t af[8];
#pragma unroll
  for (int ks = 0; ks < 8; ++ks) af[ks] = *(const h4_t*)&As[w*16 + lr][ks*16 + lg*4];
  int row0 = rt*64 + w*16 + lg*4;              // + r
#pragma unroll
  for (int ns = 0; ns < 4; ++ns) {
    f4_t acc = (f4_t){0.f,0.f,0.f,0.f};
#pragma unroll
    for (int ks = 0; ks < 8; ++ks) {
      h4_t bf = *(const h4_t*)&Ws[ns*16 + lr][ks*16 + lg*4];
      acc = __builtin_amdgcn_mfma_f32_16x16x16f16(af[ks], bf, acc, 0, 0, 0);
    }
    int c = slab*64 + ns*16 + lr;
    float bias = bcat[c];
    if (mode == 0) {
      float g0 = gamma[c], g1 = gamma[64+c], be0 = beta[c], be1 = beta[64+c];
#pragma unroll
      for (int r = 0; r < 4; ++r) {
        float qk = siluf_(acc[r] + bias);
        size_t row = row0 + r;
        qh[row*DQK_ + c] = (_Float16)(qk*g0 + be0);
        kh[row*DQK_ + c] = (_Float16)(qk*g1 + be1);
      }
    } else if (mode == 1) {
      int cl = c - 64;
      int bb = row0 >> 12, rl = row0 & 4095;
      h4_t vv;
#pragma unroll
      for (int r = 0; r < 4; ++r) vv[r] = (_Float16)siluf_(acc[r] + bias);
      *(h4_t*)&vT[((size_t)bb*DV_ + cl)*N_ + rl] = vv;
    } else if (mode == 2) {
      int cl = c - 320;
#pragma unroll
      for (int r = 0; r < 4; ++r) resetb[(size_t)(row0 + r)*DV_ + cl] = siluf_(acc[r] + bias);
    } else if (mode == 3) {
      int cl = c - 576;
#pragma unroll
      for (int r = 0; r < 4; ++r) updateb[(size_t)(row0 + r)*D_ + cl] = sigmoidf_(acc[r] + bias);
    } else {
      int cl = c - 704;
#pragma unroll
      for (int r = 0; r < 4; ++r) hemab[(size_t)(row0 + r)*D_ + cl] = acc[r] + bias;
    }
  }
}

// ---------------- attention: laplacian(QK^T/n + bias[i-j]) @ V, causal ----------------
// grid 1024 = 64(it, largest-first) x 8(split) x 2(b). block 256 = 4 waves x 16 rows.
// Swapped MFMA: S^T = mfma(K, Q) puts P directly in the PV A-fragment layout.
__global__ __launch_bounds__(256) void attn_kernel(
    const _Float16* __restrict__ qh, const _Float16* __restrict__ kh,
    const _Float16* __restrict__ vT, const float* __restrict__ biasT,
    float* __restrict__ attnp) {
  int bid = blockIdx.x;
  int b = bid & 1;
  int s = (bid >> 1) & 7;
  int it = 63 - (bid >> 4);
  int njt = it + 1;
  int nblk = (njt + 7) >> 3;
  if (s >= nblk) return;
  int jlo = s*8, jhi = min(jlo + 8, njt);
  int q_ = it >> 3, r_ = it & 7;
  int slot = 4*q_*(q_+1) + r_*(q_+1) + s;       // compact partial index
  int i0 = it * 64;
  int lane = threadIdx.x & 63, w = threadIdx.x >> 6;
  int lr = lane & 15, lg = lane >> 4;

  __shared__ _Float16 Klds[64][72];
  __shared__ _Float16 VTs[256][72];

  h4_t qf[4];
  const _Float16* qp = qh + ((size_t)b*N_ + i0 + w*16 + lr)*DQK_;
#pragma unroll
  for (int ks = 0; ks < 4; ++ks) qf[ks] = *(const h4_t*)(qp + ks*16 + lg*4);

  f4_t accO[16];
#pragma unroll
  for (int i = 0; i < 16; ++i) accO[i] = (f4_t){0.f,0.f,0.f,0.f};

  for (int jt = jlo; jt < jhi; ++jt) {
    int j0 = jt * 64;
    __syncthreads();
    {
      const h8_t* k8 = (const h8_t*)(kh + ((size_t)b*N_ + j0)*DQK_);
#pragma unroll
      for (int i = 0; i < 2; ++i) {
        int idx = threadIdx.x + i*256;
        int row = idx >> 3, seg = idx & 7;
        *(h8_t*)&Klds[row][seg*8] = k8[idx];
      }
      const _Float16* vtb = vT + (size_t)b*DV_*N_ + j0;
#pragma unroll
      for (int i = 0; i < 8; ++i) {
        int idx = threadIdx.x + i*256;
        int row = idx >> 3, seg = idx & 7;
        *(h8_t*)&VTs[row][seg*8] = *(const h8_t*)(vtb + (size_t)row*N_ + seg*8);
      }
    }
    __syncthreads();

#pragma unroll
    for (int ns = 0; ns < 4; ++ns) {
      // S^T block: rows j, cols i  (A = K rows, B = Q^T)
      f4_t accS = (f4_t){0.f,0.f,0.f,0.f};
#pragma unroll
      for (int ks = 0; ks < 4; ++ks) {
        h4_t kf = *(const h4_t*)&Klds[ns*16 + lr][ks*16 + lg*4];
        accS = __builtin_amdgcn_mfma_f32_16x16x16f16(kf, qf[ks], accS, 0, 0, 0);
      }
      int jbase = j0 + ns*16 + lg*4;            // + r
      int irow  = i0 + w*16 + lr;
      h4_t pa;
#pragma unroll
      for (int r = 0; r < 4; ++r) {
        int delta = irow - (jbase + r);
        int dd = delta < 0 ? 0 : delta;
        float z = accS[r]*(1.f/4096.f) + biasT[dd];
        float pv = 0.5f*(1.f + erff((z - 0.70710678f)*0.79788456f));
        pa[r] = (_Float16)(delta < 0 ? 0.f : pv);
      }
      // O += P(:, this 16-j-slice) @ V(this 16-j-slice, :)
#pragma unroll
      for (int ns2 = 0; ns2 < 16; ++ns2) {
        h4_t vf = *(const h4_t*)&VTs[ns2*16 + lr][ns*16 + lg*4];
        accO[ns2] = __builtin_amdgcn_mfma_f32_16x16x16f16(pa, vf, accO[ns2], 0, 0, 0);
      }
    }
  }

  float* op = attnp + ((size_t)b*288 + slot)*64*DV_;
#pragma unroll
  for (int ns2 = 0; ns2 < 16; ++ns2) {
#pragma unroll
    for (int r = 0; r < 4; ++r) {
      op[(size_t)(w*16 + lg*4 + r)*DV_ + ns2*16 + lr] = accO[ns2][r];
    }
  }
}

// gatedh = (sum of valid attn partials) * reset, cast to f16
__global__ void combine_gated(const float* __restrict__ attnp, const float* __restrict__ resetb,
                              _Float16* __restrict__ gatedh) {
  size_t fi = (size_t)blockIdx.x*256 + threadIdx.x;   // f4 index over 8192*256
  int rr = (int)(fi >> 6);
  int c4 = (int)(fi & 63);
  int b = rr >> 12, rowInB = rr & 4095;
  int it = rowInB >> 6, rowLocal = rowInB & 63;
  int nblk = (it + 8) >> 3;
  int q_ = it >> 3, r_ = it & 7;
  int base = 4*q_*(q_+1) + r_*(q_+1);
  const f4_t* ap = (const f4_t*)attnp;
  size_t rowOff = ((size_t)b*288 + base)*64 + rowLocal;
  f4_t acc = (f4_t){0.f,0.f,0.f,0.f};
  for (int s = 0; s < nblk; ++s)
    acc += ap[(rowOff + (size_t)s*64)*64 + c4];
  f4_t rg = ((const f4_t*)resetb)[fi];
  f4_t g = acc * rg;
  h4_t hg;
#pragma unroll
  for (int j = 0; j < 4; ++j) hg[j] = (_Float16)g[j];
  *(h4_t*)(gatedh + fi*4) = hg;
}

// ---------------- final: H = silu(hemab + gated@Uh); out = u*H + (1-u)*x ----------------
// MFMA GEMM [8192 x 256] @ [256 x 128]. grid 256 = 128 rowtiles x 2 colslabs.
// block 256 = 4 waves; K staged in 2 chunks of 128.
__global__ __launch_bounds__(256) void final_mfma(
    const _Float16* __restrict__ gatedh, const _Float16* __restrict__ Uht,
    const float* __restrict__ hemab, const float* __restrict__ updateb,
    const float* __restrict__ x, float* __restrict__ out) {
  int rt = blockIdx.x >> 1, cs = blockIdx.x & 1;
  int tid = threadIdx.x;
  int lane = tid & 63, w = tid >> 6;
  int lr = lane & 15, lg = lane >> 4;
  int row0 = rt*64, c0 = cs*64;
  __shared__ _Float16 As[64][136];
  __shared__ _Float16 Ws[64][136];
  f4_t acc[4];
#pragma unroll
  for (int ns = 0; ns < 4; ++ns) acc[ns] = (f4_t){0.f,0.f,0.f,0.f};
#pragma unroll
  for (int kc = 0; kc < 2; ++kc) {
    __syncthreads();
#pragma unroll
    for (int i = 0; i < 4; ++i) {
      int idx = tid + i*256;
      int row = idx >> 4, seg = idx & 15;
      *(h8_t*)&As[row][seg*8] =
          *(const h8_t*)(gatedh + (size_t)(row0 + row)*DV_ + kc*128 + seg*8);
      *(h8_t*)&Ws[row][seg*8] =
          *(const h8_t*)(Uht + (size_t)(c0 + row)*DV_ + kc*128 + seg*8);
    }
    __syncthreads();
    h4_t af[8];
#pragma unroll
    for (int ks = 0; ks < 8; ++ks) af[ks] = *(const h4_t*)&As[w*16 + lr][ks*16 + lg*4];
#pragma unroll
    for (int ns = 0; ns < 4; ++ns) {
#pragma unroll
      for (int ks = 0; ks < 8; ++ks) {
        h4_t bf = *(const h4_t*)&Ws[ns*16 + lr][ks*16 + lg*4];
        acc[ns] = __builtin_amdgcn_mfma_f32_16x16x16f16(af[ks], bf, acc[ns], 0, 0, 0);
      }
    }
  }
  int orow = row0 + w*16 + lg*4;               // + r
#pragma unroll
  for (int ns = 0; ns < 4; ++ns) {
    int col = c0 + ns*16 + lr;
#pragma unroll
    for (int r = 0; r < 4; ++r) {
      size_t o = (size_t)(orow + r)*D_ + col;
      float z = acc[ns][r] + hemab[o];
      float Hv = siluf_(z);
      float u  = updateb[o];
      out[o] = u*Hv + (1.f - u)*x[o];
    }
  }
}

extern "C" void kernel_launch(void* const* d_in, const int* in_sizes, int n_in,
                              void* d_out, int out_size, void* d_ws, size_t ws_size,
                              hipStream_t stream) {
  (void)in_sizes; (void)n_in; (void)out_size; (void)ws_size;
  const float* x         = (const float*)d_in[0];
  const float* expansion = (const float*)d_in[1];
  const float* reduction = (const float*)d_in[2];
  const float* alphas    = (const float*)d_in[3];
  const float* dampen    = (const float*)d_in[4];
  const float* Wqk       = (const float*)d_in[5];
  const float* bqk       = (const float*)d_in[6];
  const float* gamma     = (const float*)d_in[7];
  const float* beta      = (const float*)d_in[8];
  const float* Wv        = (const float*)d_in[9];
  const float* bv        = (const float*)d_in[10];
  const float* rel_table = (const float*)d_in[11];
  const float* Wr        = (const float*)d_in[12];
  const float* br        = (const float*)d_in[13];
  const float* Wu        = (const float*)d_in[14];
  const float* bu        = (const float*)d_in[15];
  const float* Wh        = (const float*)d_in[16];
  const float* Uh        = (const float*)d_in[17];
  const float* bh        = (const float*)d_in[18];
  float* out = (float*)d_out;

  char* p = (char*)d_ws;
  size_t off = 0;
  auto alloc = [&](size_t bytes) -> char* {
    char* r = p + off;
    off += (bytes + 255) & ~(size_t)255;
    return r;
  };
  float*    F      = (float*)alloc((size_t)B_*H_*D_*64*4);
  float*    carry  = (float*)alloc((size_t)B_*H_*D_*64*4);
  float*    ema    = (float*)alloc((size_t)B_*N_*D_*4);
  _Float16* emah   = (_Float16*)alloc((size_t)B_*N_*D_*2);
  _Float16* xh     = (_Float16*)alloc((size_t)B_*N_*D_*2);
  float*    biasT  = (float*)alloc((size_t)N_*4);
  _Float16* Wt     = (_Float16*)alloc((size_t)832*128*2);
  float*    bcat   = (float*)alloc((size_t)832*4);
  _Float16* Uht    = (_Float16*)alloc((size_t)D_*DV_*2);
  _Float16* qh     = (_Float16*)alloc((size_t)B_*N_*DQK_*2);
  _Float16* kh     = (_Float16*)alloc((size_t)B_*N_*DQK_*2);
  _Float16* vT     = (_Float16*)alloc((size_t)B_*DV_*N_*2);
  float*    resetb = (float*)alloc((size_t)B_*N_*DV_*4);
  float*    updateb= (float*)alloc((size_t)B_*N_*D_*4);
  float*    hemab  = (float*)alloc((size_t)B_*N_*D_*4);
  _Float16* gatedh = (_Float16*)alloc((size_t)B_*N_*DV_*2);
  float*    attnp  = (float*)alloc((size_t)B_*288*64*DV_*4);

  prep_weights<<<416, 256, 0, stream>>>(Wqk, Wv, Wr, Wu, Wh, bqk, bv, br, bu, bh, Wt, bcat);
  prep_uh<<<128, 256, 0, stream>>>(Uh, Uht);
  bias_table<<<16, 256, 0, stream>>>(rel_table, biasT);
  ema_phase1<<<1024, 256, 0, stream>>>(x, expansion, alphas, dampen, F, xh);
  ema_carry<<<16, 256, 0, stream>>>(F, alphas, dampen, carry);
  ema_phase2<<<1024, 256, 0, stream>>>(x, expansion, reduction, alphas, dampen, carry, ema, emah);
  linear_mfma<<<128*13, 256, 0, stream>>>(emah, xh, Wt, bcat, gamma, beta,
                                          qh, kh, vT, resetb, updateb, hemab);
  attn_kernel<<<1024, 256, 0, stream>>>(qh, kh, vT, biasT, attnp);
  combine_gated<<<2048, 256, 0, stream>>>(attnp, resetb, gatedh);
  final_mfma<<<256, 256, 0, stream>>>(gatedh, Uht, hemab, updateb, x, out);
}